// Round 8
// baseline (183.510 us; speedup 1.0000x reference)
//
#include <hip/hip_runtime.h>

typedef float f32x4 __attribute__((ext_vector_type(4)));
typedef float f32x2 __attribute__((ext_vector_type(2)));
typedef short bf16x8 __attribute__((ext_vector_type(8)));

#define LOG2E 1.4426950408889634f

__device__ __forceinline__ unsigned short f2bf(float f) {
  return __builtin_bit_cast(unsigned short, (__bf16)f);
}

// ---------------------------------------------------------------------------
// ws layout:
//   [0]    double accum          (zeroed by memset node)
//   [16]   uint   done_main      (zeroed by memset node)
//   [24]   uint   done_prep      (zeroed by memset node)
//   [32]   float  nc0s           (written by k_prep last block)
//   [512]  float  Spart[64]
//   [1024] float  partialT[256][64]   (column-sum partials, transposed)
//   [66560]  float sq[8192]
//   [131072] ushort Vbf[8192*256]     (bf16 cache of concat(src,tgt))
// ---------------------------------------------------------------------------

// K1: prep — row sum-of-squares, bf16 cast, column-sum partials; the LAST
// block (done-counter) reduces partials to the bandwidth constant nc0s.
__global__ __launch_bounds__(1024) void k_prep(
    const float* __restrict__ src, const float* __restrict__ tgt,
    float* __restrict__ sq, unsigned short* __restrict__ Vbf,
    float* __restrict__ partialT, float* __restrict__ Spart,
    unsigned int* __restrict__ done_prep, float* __restrict__ nc0sp) {
  const int t = threadIdx.x, lane = t & 63, w = t >> 6, b = blockIdx.x;
  __shared__ float cpart[16][256];
  __shared__ float sredS[16];
  __shared__ unsigned int islast;
  __shared__ float sS;

  const int row0 = b * 128 + w * 8;
  f32x4 colacc = {0.f, 0.f, 0.f, 0.f};
  float Sp = 0.f;
  for (int i = 0; i < 8; ++i) {
    const int row = row0 + i;
    const float* rowp = (row < 4096) ? src + (size_t)row * 256
                                     : tgt + (size_t)(row - 4096) * 256;
    float4 v = ((const float4*)rowp)[lane];
    colacc[0] += v.x; colacc[1] += v.y; colacc[2] += v.z; colacc[3] += v.w;
    float ss = v.x * v.x + v.y * v.y + v.z * v.z + v.w * v.w;
    #pragma unroll
    for (int m = 32; m >= 1; m >>= 1) ss += __shfl_xor(ss, m, 64);
    if (lane == 0) { sq[row] = ss; Sp += ss; }
    ushort4 p;
    p.x = f2bf(v.x); p.y = f2bf(v.y); p.z = f2bf(v.z); p.w = f2bf(v.w);
    ((ushort4*)Vbf)[(size_t)row * 64 + lane] = p;
  }
  *(f32x4*)&cpart[w][lane * 4] = colacc;
  if (lane == 0) sredS[w] = Sp;
  __syncthreads();
  if (t < 256) {
    float pt = 0.f;
    #pragma unroll
    for (int ww = 0; ww < 16; ++ww) pt += cpart[ww][t];
    partialT[t * 64 + b] = pt;
  }
  if (t == 0) {
    float s = 0.f;
    #pragma unroll
    for (int ww = 0; ww < 16; ++ww) s += sredS[ww];
    Spart[b] = s;
  }
  __syncthreads();               // drains this block's global stores
  if (t == 0) {
    __threadfence();             // release
    islast = (atomicAdd(done_prep, 1u) == 63u) ? 1u : 0u;
  }
  __syncthreads();
  if (islast) {
    __threadfence();             // acquire before reading other blocks' stores
    const int col = t & 255, seg = t >> 8;
    float cs = 0.f;
    #pragma unroll
    for (int j = 0; j < 16; ++j) cs += partialT[col * 64 + seg * 16 + j];
    cpart[seg][col] = cs;
    __syncthreads();
    float Cp = 0.f, Sv = 0.f;
    if (t < 256) {
      const float ctot = cpart[0][t] + cpart[1][t] + cpart[2][t] + cpart[3][t];
      Cp = ctot * ctot;
    }
    if (t < 64) Sv = Spart[t];
    #pragma unroll
    for (int m = 32; m >= 1; m >>= 1) {
      Cp += __shfl_xor(Cp, m, 64);
      Sv += __shfl_xor(Sv, m, 64);
    }
    if (lane == 0) sredS[w] = Cp;
    if (t == 0) sS = Sv;
    __syncthreads();
    if (t == 0) {
      const float CSQ = sredS[0] + sredS[1] + sredS[2] + sredS[3];
      const float sum_l2 = 2.f * 8192.f * sS - 2.f * CSQ;
      const float bw = sum_l2 / (8192.f * 8192.f - 8192.f) * 0.25f;
      *nc0sp = -LOG2E / bw * 0.0625f;   // -log2(e)/bw/16 (exp2-squaring form)
    }
  }
}

// ---------------------------------------------------------------------------
// K2: main — LDS-free, barrier-free MFMA Gram. Each wave owns a 64x64 tile;
// fragments loaded straight from global (L2-resident bf16 panels), 1-deep
// cur/nxt prefetch. Fused 5-kernel gaussian (1 exp2 + 4 squarings) + signed
// reduce + last-block finalize. Grid: 2080 upper-triangular 128x128 regions,
// 4 waves each (2x2 of 64x64).
// ---------------------------------------------------------------------------
__global__ __launch_bounds__(256) void k_main(
    const unsigned short* __restrict__ Vbf, const float* __restrict__ sq,
    const float* __restrict__ nc0sp, double* __restrict__ accum,
    unsigned int* __restrict__ done, float* __restrict__ out) {
  // decode linear block id -> (r,c) in upper triangle of 64x64 region grid
  const int bid = blockIdx.x;
  int r = (int)((129.0f - sqrtf(16641.0f - 8.0f * (float)bid)) * 0.5f);
  int base = (r * (129 - r)) >> 1;
  if (bid < base)                { --r; base = (r * (129 - r)) >> 1; }
  else if (bid - base >= 64 - r) { ++r; base = (r * (129 - r)) >> 1; }
  const int c = r + (bid - base);
  const int i0 = r * 128, j0 = c * 128;

  const int t = threadIdx.x, lane = t & 63, w = t >> 6;
  const int wr = w >> 1, wc = w & 1;

  // per-lane fragment base: row (lane&15) of the wave's 64-row panel,
  // k-slot (lane>>4) within each 64B (=32-elem) k-step.
  const char* Vb = (const char*)Vbf;
  const char* pA = Vb + (size_t)(i0 + wr * 64 + (lane & 15)) * 512 + ((lane >> 4) << 4);
  const char* pB = Vb + (size_t)(j0 + wc * 64 + (lane & 15)) * 512 + ((lane >> 4) << 4);

  f32x4 acc[4][4] = {};
  bf16x8 ac[4], bc[4];
  #pragma unroll
  for (int m = 0; m < 4; ++m) {
    ac[m] = *(const bf16x8*)(pA + m * 8192);
    bc[m] = *(const bf16x8*)(pB + m * 8192);
  }
  #pragma unroll
  for (int ks = 0; ks < 8; ++ks) {
    bf16x8 an[4], bn[4];
    if (ks < 7) {
      #pragma unroll
      for (int m = 0; m < 4; ++m) {
        an[m] = *(const bf16x8*)(pA + m * 8192 + (ks + 1) * 64);
        bn[m] = *(const bf16x8*)(pB + m * 8192 + (ks + 1) * 64);
      }
    }
    #pragma unroll
    for (int m = 0; m < 4; ++m)
      #pragma unroll
      for (int n = 0; n < 4; ++n)
        acc[m][n] = __builtin_amdgcn_mfma_f32_16x16x32_bf16(ac[m], bc[n], acc[m][n], 0, 0, 0);
    if (ks < 7) {
      #pragma unroll
      for (int m = 0; m < 4; ++m) { ac[m] = an[m]; bc[m] = bn[m]; }
    }
  }

  // ---- epilogue: l2 -> e=exp2(l2*nc0s) -> e+e^2+e^4+e^8+e^16, signed sum ----
  const float nc0s = *nc0sp;
  float rsv[16];
  const int rbase = i0 + wr * 64 + ((lane >> 4) << 2);
  #pragma unroll
  for (int m = 0; m < 4; ++m) {
    const float4 q = *(const float4*)(sq + rbase + m * 16);
    rsv[m * 4 + 0] = q.x; rsv[m * 4 + 1] = q.y;
    rsv[m * 4 + 2] = q.z; rsv[m * 4 + 3] = q.w;
  }
  float cs[4];
  const int cbase = j0 + wc * 64 + (lane & 15);
  #pragma unroll
  for (int n = 0; n < 4; ++n) cs[n] = sq[cbase + n * 16];

  f32x2 ks2 = {0.f, 0.f};
  #pragma unroll
  for (int m = 0; m < 4; ++m)
    #pragma unroll
    for (int n = 0; n < 4; ++n)
      #pragma unroll
      for (int h = 0; h < 2; ++h) {
        f32x2 g  = { acc[m][n][2 * h], acc[m][n][2 * h + 1] };
        f32x2 rc = { rsv[m * 4 + 2 * h] + cs[n], rsv[m * 4 + 2 * h + 1] + cs[n] };
        f32x2 l2 = __builtin_elementwise_max(rc - 2.f * g, (f32x2){0.f, 0.f});
        f32x2 tt = l2 * nc0s;
        f32x2 e;
        e[0] = __builtin_amdgcn_exp2f(tt[0]);
        e[1] = __builtin_amdgcn_exp2f(tt[1]);
        f32x2 s = e;
        f32x2 e2 = e * e;   s += e2;
        f32x2 e4 = e2 * e2; s += e4;
        f32x2 e8 = e4 * e4; s += e8;
        s += e8 * e8;
        ks2 += s;
      }
  float ksum = ks2[0] + ks2[1];
  #pragma unroll
  for (int m = 32; m >= 1; m >>= 1) ksum += __shfl_xor(ksum, m, 64);

  __shared__ float redf[4];
  if (lane == 0) redf[w] = ksum;
  __syncthreads();
  if (t == 0) {
    const float sign = ((r < 32) == (c < 32)) ? 1.0f : -1.0f;
    const float mult = (r == c) ? 1.0f : 2.0f;
    const double contrib =
        (double)((redf[0] + redf[1] + redf[2] + redf[3]) * sign * mult);
    atomicAdd(accum, contrib);
    __threadfence();
    const unsigned int old = atomicAdd(done, 1u);
    if (old == 2079u) {
      __threadfence();
      const double tot = atomicAdd(accum, 0.0);   // coherent read-back
      out[0] = (float)(tot * (1.0 / 16777216.0));
    }
  }
}

// ---------------------------------------------------------------------------
extern "C" void kernel_launch(void* const* d_in, const int* in_sizes, int n_in,
                              void* d_out, int out_size, void* d_ws, size_t ws_size,
                              hipStream_t stream) {
  const float* src = (const float*)d_in[0];
  const float* tgt = (const float*)d_in[1];
  char* ws = (char*)d_ws;
  double*         accum     = (double*)ws;
  unsigned int*   done_main = (unsigned int*)(ws + 16);
  unsigned int*   done_prep = (unsigned int*)(ws + 24);
  float*          nc0s      = (float*)(ws + 32);
  float*          Spart     = (float*)(ws + 512);
  float*          partialT  = (float*)(ws + 1024);
  float*          sq        = (float*)(ws + 66560);
  unsigned short* Vbf       = (unsigned short*)(ws + 131072);
  float* out = (float*)d_out;

  hipMemsetAsync(ws, 0, 64, stream);   // accum, done_main, done_prep, nc0s
  hipLaunchKernelGGL(k_prep, dim3(64),   dim3(1024), 0, stream,
                     src, tgt, sq, Vbf, partialT, Spart, done_prep, nc0s);
  hipLaunchKernelGGL(k_main, dim3(2080), dim3(256),  0, stream,
                     Vbf, sq, nc0s, accum, done_main, out);
}

// Round 9
// 109.135 us; speedup vs baseline: 1.6815x; 1.6815x over previous
//
#include <hip/hip_runtime.h>

typedef float f32x4 __attribute__((ext_vector_type(4)));
typedef float f32x2 __attribute__((ext_vector_type(2)));
typedef short bf16x8 __attribute__((ext_vector_type(8)));

#define LOG2E 1.4426950408889634f

__device__ __forceinline__ unsigned short f2bf(float f) {
  return __builtin_bit_cast(unsigned short, (__bf16)f);
}

// ---------------------------------------------------------------------------
// ws layout:
//   [0]      double accum        (unused this round; memset keeps layout)
//   [24]     uint   done_prep    (zeroed by memset node)
//   [32]     float  nc0s         (written by k_prep last block)
//   [512]    float  Spart[64]
//   [1024]   float  partialT[256][64]
//   [66560]  float  sq[8192]
//   [99328]  float  block_out[2080]   (per-block signed partials — NO atomics)
//   [131072] ushort Vbf[8192*256]     (bf16 cache of concat(src,tgt))
// ---------------------------------------------------------------------------

// K1: prep — row sum-of-squares, bf16 cast, column-sum partials; the LAST
// block (64-way done-counter, negligible contention) reduces to nc0s.
__global__ __launch_bounds__(1024) void k_prep(
    const float* __restrict__ src, const float* __restrict__ tgt,
    float* __restrict__ sq, unsigned short* __restrict__ Vbf,
    float* __restrict__ partialT, float* __restrict__ Spart,
    unsigned int* __restrict__ done_prep, float* __restrict__ nc0sp) {
  const int t = threadIdx.x, lane = t & 63, w = t >> 6, b = blockIdx.x;
  __shared__ float cpart[16][256];
  __shared__ float sredS[16];
  __shared__ unsigned int islast;
  __shared__ float sS;

  const int row0 = b * 128 + w * 8;
  f32x4 colacc = {0.f, 0.f, 0.f, 0.f};
  float Sp = 0.f;
  for (int i = 0; i < 8; ++i) {
    const int row = row0 + i;
    const float* rowp = (row < 4096) ? src + (size_t)row * 256
                                     : tgt + (size_t)(row - 4096) * 256;
    float4 v = ((const float4*)rowp)[lane];
    colacc[0] += v.x; colacc[1] += v.y; colacc[2] += v.z; colacc[3] += v.w;
    float ss = v.x * v.x + v.y * v.y + v.z * v.z + v.w * v.w;
    #pragma unroll
    for (int m = 32; m >= 1; m >>= 1) ss += __shfl_xor(ss, m, 64);
    if (lane == 0) { sq[row] = ss; Sp += ss; }
    ushort4 p;
    p.x = f2bf(v.x); p.y = f2bf(v.y); p.z = f2bf(v.z); p.w = f2bf(v.w);
    ((ushort4*)Vbf)[(size_t)row * 64 + lane] = p;
  }
  *(f32x4*)&cpart[w][lane * 4] = colacc;
  if (lane == 0) sredS[w] = Sp;
  __syncthreads();
  if (t < 256) {
    float pt = 0.f;
    #pragma unroll
    for (int ww = 0; ww < 16; ++ww) pt += cpart[ww][t];
    partialT[t * 64 + b] = pt;
  }
  if (t == 0) {
    float s = 0.f;
    #pragma unroll
    for (int ww = 0; ww < 16; ++ww) s += sredS[ww];
    Spart[b] = s;
  }
  __syncthreads();               // drains this block's global stores
  if (t == 0) {
    __threadfence();             // release
    islast = (atomicAdd(done_prep, 1u) == 63u) ? 1u : 0u;
  }
  __syncthreads();
  if (islast) {
    __threadfence();             // acquire before reading other blocks' stores
    const int col = t & 255, seg = t >> 8;
    float cs = 0.f;
    #pragma unroll
    for (int j = 0; j < 16; ++j) cs += partialT[col * 64 + seg * 16 + j];
    cpart[seg][col] = cs;
    __syncthreads();
    float Cp = 0.f, Sv = 0.f;
    if (t < 256) {
      const float ctot = cpart[0][t] + cpart[1][t] + cpart[2][t] + cpart[3][t];
      Cp = ctot * ctot;
    }
    if (t < 64) Sv = Spart[t];
    #pragma unroll
    for (int m = 32; m >= 1; m >>= 1) {
      Cp += __shfl_xor(Cp, m, 64);
      Sv += __shfl_xor(Sv, m, 64);
    }
    if (lane == 0) sredS[w] = Cp;
    if (t == 0) sS = Sv;
    __syncthreads();
    if (t == 0) {
      const float CSQ = sredS[0] + sredS[1] + sredS[2] + sredS[3];
      const float sum_l2 = 2.f * 8192.f * sS - 2.f * CSQ;
      const float bw = sum_l2 / (8192.f * 8192.f - 8192.f) * 0.25f;
      *nc0sp = -LOG2E / bw * 0.0625f;   // -log2(e)/bw/16 (exp2-squaring form)
    }
  }
}

// ---------------------------------------------------------------------------
// K2: main — R1's reg-staged swizzled-LDS MFMA loop (empirically fastest) +
// exp2-squaring epilogue + per-block PLAIN STORE of the signed partial
// (no same-address atomics, no done-counter). Grid: 2080 triangular tiles.
// ---------------------------------------------------------------------------
__global__ __launch_bounds__(256) void k_main(
    const unsigned short* __restrict__ Vbf, const float* __restrict__ sq,
    const float* __restrict__ nc0sp, float* __restrict__ block_out) {
  // decode linear block id -> (r,c) in upper triangle of 64x64
  const int bid = blockIdx.x;
  int r = (int)((129.0f - sqrtf(16641.0f - 8.0f * (float)bid)) * 0.5f);
  int base = (r * (129 - r)) >> 1;
  if (bid < base)                { --r; base = (r * (129 - r)) >> 1; }
  else if (bid - base >= 64 - r) { ++r; base = (r * (129 - r)) >> 1; }
  const int c = r + (bid - base);
  const int i0 = r * 128, j0 = c * 128;

  const int t = threadIdx.x, lane = t & 63, w = t >> 6;
  const int wr = w >> 1, wc = w & 1;

  __shared__ uint4 lds4[2048];           // exactly 32 KB
  char* As = (char*)lds4;
  char* Bs = (char*)lds4 + 16384;
  float* redf = (float*)lds4;            // reused only after the final barrier

  const unsigned short* VA = Vbf + (size_t)i0 * 256;
  const unsigned short* VB = Vbf + (size_t)j0 * 256;

  const float nc0s = *nc0sp;

  f32x4 acc[4][4] = {};
  const int srow = t >> 3;               // 0..31
  const int scb  = (t & 7) * 16;         // byte offset in 128B slab

  for (int ks = 0; ks < 4; ++ks) {
    const int kc = ks * 64;
    __syncthreads();
    #pragma unroll
    for (int it = 0; it < 4; ++it) {
      const int rr = it * 32 + srow;
      const int dst = rr * 128 + (scb ^ ((rr & 7) << 4));
      uint4 ga = *(const uint4*)(VA + (size_t)rr * 256 + kc + (scb >> 1));
      uint4 gb = *(const uint4*)(VB + (size_t)rr * 256 + kc + (scb >> 1));
      *(uint4*)(As + dst) = ga;
      *(uint4*)(Bs + dst) = gb;
    }
    __syncthreads();
    #pragma unroll
    for (int kk = 0; kk < 2; ++kk) {
      const int kbyte = kk * 64 + ((lane >> 4) << 4);
      bf16x8 a[4], b[4];
      #pragma unroll
      for (int m = 0; m < 4; ++m) {
        const int ra = wr * 64 + m * 16 + (lane & 15);
        a[m] = *(const bf16x8*)(As + ra * 128 + (kbyte ^ ((ra & 7) << 4)));
        const int rb = wc * 64 + m * 16 + (lane & 15);
        b[m] = *(const bf16x8*)(Bs + rb * 128 + (kbyte ^ ((rb & 7) << 4)));
      }
      #pragma unroll
      for (int m = 0; m < 4; ++m)
        #pragma unroll
        for (int n = 0; n < 4; ++n)
          acc[m][n] = __builtin_amdgcn_mfma_f32_16x16x32_bf16(a[m], b[n], acc[m][n], 0, 0, 0);
    }
  }

  // ---- epilogue: l2 -> e=exp2(l2*nc0s) -> e+e^2+e^4+e^8+e^16, signed sum ----
  float rsv[16];
  const int rbase = i0 + wr * 64 + ((lane >> 4) << 2);
  #pragma unroll
  for (int m = 0; m < 4; ++m) {
    const float4 q = *(const float4*)(sq + rbase + m * 16);
    rsv[m * 4 + 0] = q.x; rsv[m * 4 + 1] = q.y;
    rsv[m * 4 + 2] = q.z; rsv[m * 4 + 3] = q.w;
  }
  float cs[4];
  const int cbase = j0 + wc * 64 + (lane & 15);
  #pragma unroll
  for (int n = 0; n < 4; ++n) cs[n] = sq[cbase + n * 16];

  f32x2 ks2 = {0.f, 0.f};
  #pragma unroll
  for (int m = 0; m < 4; ++m)
    #pragma unroll
    for (int n = 0; n < 4; ++n)
      #pragma unroll
      for (int h = 0; h < 2; ++h) {
        f32x2 g  = { acc[m][n][2 * h], acc[m][n][2 * h + 1] };
        f32x2 rc = { rsv[m * 4 + 2 * h] + cs[n], rsv[m * 4 + 2 * h + 1] + cs[n] };
        f32x2 l2 = __builtin_elementwise_max(rc - 2.f * g, (f32x2){0.f, 0.f});
        f32x2 tt = l2 * nc0s;
        f32x2 e;
        e[0] = __builtin_amdgcn_exp2f(tt[0]);
        e[1] = __builtin_amdgcn_exp2f(tt[1]);
        f32x2 s = e;
        f32x2 e2 = e * e;   s += e2;
        f32x2 e4 = e2 * e2; s += e4;
        f32x2 e8 = e4 * e4; s += e8;
        s += e8 * e8;
        ks2 += s;
      }
  float ksum = ks2[0] + ks2[1];
  #pragma unroll
  for (int m = 32; m >= 1; m >>= 1) ksum += __shfl_xor(ksum, m, 64);

  __syncthreads();                       // all waves done reading LDS tiles
  if (lane == 0) redf[w] = ksum;
  __syncthreads();
  if (t == 0) {
    const float sign = ((r < 32) == (c < 32)) ? 1.0f : -1.0f;
    const float mult = (r == c) ? 1.0f : 2.0f;
    block_out[bid] = (redf[0] + redf[1] + redf[2] + redf[3]) * sign * mult;
  }
}

// ---------------------------------------------------------------------------
// K3: reduce 2080 per-block partials (double) -> final scalar / 4096^2.
// ---------------------------------------------------------------------------
__global__ __launch_bounds__(256) void k_reduce(
    const float* __restrict__ block_out, float* __restrict__ out) {
  const int t = threadIdx.x, lane = t & 63, w = t >> 6;
  double s = 0.0;
  for (int i = t; i < 2080; i += 256) s += (double)block_out[i];
  #pragma unroll
  for (int m = 32; m >= 1; m >>= 1) s += __shfl_xor(s, m, 64);
  __shared__ double rd[4];
  if (lane == 0) rd[w] = s;
  __syncthreads();
  if (t == 0)
    out[0] = (float)((rd[0] + rd[1] + rd[2] + rd[3]) * (1.0 / 16777216.0));
}

// ---------------------------------------------------------------------------
extern "C" void kernel_launch(void* const* d_in, const int* in_sizes, int n_in,
                              void* d_out, int out_size, void* d_ws, size_t ws_size,
                              hipStream_t stream) {
  const float* src = (const float*)d_in[0];
  const float* tgt = (const float*)d_in[1];
  char* ws = (char*)d_ws;
  unsigned int*   done_prep = (unsigned int*)(ws + 24);
  float*          nc0s      = (float*)(ws + 32);
  float*          Spart     = (float*)(ws + 512);
  float*          partialT  = (float*)(ws + 1024);
  float*          sq        = (float*)(ws + 66560);
  float*          block_out = (float*)(ws + 99328);
  unsigned short* Vbf       = (unsigned short*)(ws + 131072);
  float* out = (float*)d_out;

  hipMemsetAsync(ws, 0, 64, stream);   // done_prep (+ legacy words)
  hipLaunchKernelGGL(k_prep,   dim3(64),   dim3(1024), 0, stream,
                     src, tgt, sq, Vbf, partialT, Spart, done_prep, nc0s);
  hipLaunchKernelGGL(k_main,   dim3(2080), dim3(256),  0, stream,
                     Vbf, sq, nc0s, block_out);
  hipLaunchKernelGGL(k_reduce, dim3(1),    dim3(256),  0, stream,
                     block_out, out);
}

// Round 11
// 107.325 us; speedup vs baseline: 1.7099x; 1.0169x over previous
//
#include <hip/hip_runtime.h>

typedef float f32x4 __attribute__((ext_vector_type(4)));
typedef float f32x2 __attribute__((ext_vector_type(2)));
typedef short bf16x8 __attribute__((ext_vector_type(8)));

#define LOG2E 1.4426950408889634f

// global -> LDS direct DMA, 16B/lane; dest = wave-uniform base + lane*16
#define GLDS16(g, l) __builtin_amdgcn_global_load_lds(                       \
    (const __attribute__((address_space(1))) void*)(g),                      \
    (__attribute__((address_space(3))) void*)(l), 16, 0, 0)

__device__ __forceinline__ unsigned short f2bf(float f) {
  return __builtin_bit_cast(unsigned short, (__bf16)f);
}

// ---------------------------------------------------------------------------
// ws layout:
//   [24]     uint   done_prep    (zeroed by memset node)
//   [32]     float  nc0s         (written by k_prep last block)
//   [512]    float  Spart[64]
//   [1024]   float  partialT[256][64]
//   [66560]  float  sq[8192]
//   [99328]  float  block_out[2080]   (per-block signed partials — NO atomics)
//   [131072] ushort Vbf[8192*256]     (bf16 cache of concat(src,tgt))
// ---------------------------------------------------------------------------

// K1: prep — row sum-of-squares, bf16 cast, column-sum partials; the LAST
// block (64-way done-counter, negligible contention) reduces to nc0s.
__global__ __launch_bounds__(1024) void k_prep(
    const float* __restrict__ src, const float* __restrict__ tgt,
    float* __restrict__ sq, unsigned short* __restrict__ Vbf,
    float* __restrict__ partialT, float* __restrict__ Spart,
    unsigned int* __restrict__ done_prep, float* __restrict__ nc0sp) {
  const int t = threadIdx.x, lane = t & 63, w = t >> 6, b = blockIdx.x;
  __shared__ float cpart[16][256];
  __shared__ float sredS[16];
  __shared__ unsigned int islast;
  __shared__ float sS;

  const int row0 = b * 128 + w * 8;
  f32x4 colacc = {0.f, 0.f, 0.f, 0.f};
  float Sp = 0.f;
  for (int i = 0; i < 8; ++i) {
    const int row = row0 + i;
    const float* rowp = (row < 4096) ? src + (size_t)row * 256
                                     : tgt + (size_t)(row - 4096) * 256;
    float4 v = ((const float4*)rowp)[lane];
    colacc[0] += v.x; colacc[1] += v.y; colacc[2] += v.z; colacc[3] += v.w;
    float ss = v.x * v.x + v.y * v.y + v.z * v.z + v.w * v.w;
    #pragma unroll
    for (int m = 32; m >= 1; m >>= 1) ss += __shfl_xor(ss, m, 64);
    if (lane == 0) { sq[row] = ss; Sp += ss; }
    ushort4 p;
    p.x = f2bf(v.x); p.y = f2bf(v.y); p.z = f2bf(v.z); p.w = f2bf(v.w);
    ((ushort4*)Vbf)[(size_t)row * 64 + lane] = p;
  }
  *(f32x4*)&cpart[w][lane * 4] = colacc;
  if (lane == 0) sredS[w] = Sp;
  __syncthreads();
  if (t < 256) {
    float pt = 0.f;
    #pragma unroll
    for (int ww = 0; ww < 16; ++ww) pt += cpart[ww][t];
    partialT[t * 64 + b] = pt;
  }
  if (t == 0) {
    float s = 0.f;
    #pragma unroll
    for (int ww = 0; ww < 16; ++ww) s += sredS[ww];
    Spart[b] = s;
  }
  __syncthreads();               // drains this block's global stores
  if (t == 0) {
    __threadfence();             // release
    islast = (atomicAdd(done_prep, 1u) == 63u) ? 1u : 0u;
  }
  __syncthreads();
  if (islast) {
    __threadfence();             // acquire before reading other blocks' stores
    const int col = t & 255, seg = t >> 8;
    float cs = 0.f;
    #pragma unroll
    for (int j = 0; j < 16; ++j) cs += partialT[col * 64 + seg * 16 + j];
    cpart[seg][col] = cs;
    __syncthreads();
    float Cp = 0.f, Sv = 0.f;
    if (t < 256) {
      const float ctot = cpart[0][t] + cpart[1][t] + cpart[2][t] + cpart[3][t];
      Cp = ctot * ctot;
    }
    if (t < 64) Sv = Spart[t];
    #pragma unroll
    for (int m = 32; m >= 1; m >>= 1) {
      Cp += __shfl_xor(Cp, m, 64);
      Sv += __shfl_xor(Sv, m, 64);
    }
    if (lane == 0) sredS[w] = Cp;
    if (t == 0) sS = Sv;
    __syncthreads();
    if (t == 0) {
      const float CSQ = sredS[0] + sredS[1] + sredS[2] + sredS[3];
      const float sum_l2 = 2.f * 8192.f * sS - 2.f * CSQ;
      const float bw = sum_l2 / (8192.f * 8192.f - 8192.f) * 0.25f;
      *nc0sp = -LOG2E / bw * 0.0625f;   // -log2(e)/bw/16 (exp2-squaring form)
    }
  }
}

// ---------------------------------------------------------------------------
// K2: main — m97-style staging: BK=64, single 32KB LDS buffer, width-16
// global_load_lds (linear dest, source-side XOR swizzle: LDS[r][s]=G[r][s^(r&7)]),
// 32 MFMA/wave per barrier-pair. Epilogue sq loads hoisted above the K-loop.
// Per-block plain store of the signed partial. Grid: 2080 triangular tiles.
// ---------------------------------------------------------------------------
__global__ __launch_bounds__(256) void k_main(
    const unsigned short* __restrict__ Vbf, const float* __restrict__ sq,
    const float* __restrict__ nc0sp, float* __restrict__ block_out) {
  // decode linear block id -> (r,c) in upper triangle of 64x64
  const int bid = blockIdx.x;
  int r = (int)((129.0f - sqrtf(16641.0f - 8.0f * (float)bid)) * 0.5f);
  int base = (r * (129 - r)) >> 1;
  if (bid < base)                { --r; base = (r * (129 - r)) >> 1; }
  else if (bid - base >= 64 - r) { ++r; base = (r * (129 - r)) >> 1; }
  const int c = r + (bid - base);
  const int i0 = r * 128, j0 = c * 128;

  const int t = threadIdx.x, lane = t & 63, w = t >> 6;
  const int wr = w >> 1, wc = w & 1;

  __shared__ uint4 lds4[2048];           // exactly 32 KB: A 16K | B 16K
  char* As = (char*)lds4;
  char* Bs = (char*)lds4 + 16384;
  float* redf = (float*)lds4;            // reused only after the final barrier

  const char* VAb = (const char*)(Vbf + (size_t)i0 * 256);
  const char* VBb = (const char*)(Vbf + (size_t)j0 * 256);
  const float nc0s = *nc0sp;

  // ---- hoisted epilogue operands (hide latency under the K-loop) ----
  float rsv[16];
  const int rbase = i0 + wr * 64 + ((lane >> 4) << 2);
  #pragma unroll
  for (int m = 0; m < 4; ++m) {
    const float4 q = *(const float4*)(sq + rbase + m * 16);
    rsv[m * 4 + 0] = q.x; rsv[m * 4 + 1] = q.y;
    rsv[m * 4 + 2] = q.z; rsv[m * 4 + 3] = q.w;
  }
  float cs[4];
  const int cbase = j0 + wc * 64 + (lane & 15);
  #pragma unroll
  for (int n = 0; n < 4; ++n) cs[n] = sq[cbase + n * 16];

  // staging geometry: per wave, issue i covers 8 rows (w*32+i*8 .. +8);
  // lane -> sub-row sr=lane>>3, slot ss=lane&7; source slot pre-XORed by sr
  // so the linear DMA write yields LDS[r][s] = G[r][s ^ (r&7)].
  const int sr = lane >> 3;
  const int ss = lane & 7;
  const size_t srcoff = (size_t)(w * 32 + sr) * 512 + (size_t)((ss ^ sr) << 4);

  f32x4 acc[4][4] = {};
  const int q0 = lane >> 4;              // k-slot group 0..3
  const int la = lane & 15;

  #pragma unroll
  for (int ks = 0; ks < 4; ++ks) {
    __syncthreads();                     // prev reads done; buffer reusable
    #pragma unroll
    for (int i = 0; i < 4; ++i) {        // 4 issues A + 4 issues B per wave
      GLDS16(VAb + srcoff + (size_t)i * 8 * 512 + ks * 128, As + w * 4096 + i * 1024);
      GLDS16(VBb + srcoff + (size_t)i * 8 * 512 + ks * 128, Bs + w * 4096 + i * 1024);
    }
    __syncthreads();                     // vmcnt(0) drain + barrier: tile ready
    #pragma unroll
    for (int kk = 0; kk < 2; ++kk) {
      const int q = kk * 4 + q0;         // logical 16B k-slot 0..7
      bf16x8 a[4], b[4];
      #pragma unroll
      for (int m = 0; m < 4; ++m) {
        const int ra = wr * 64 + m * 16 + la;
        a[m] = *(const bf16x8*)(As + ra * 128 + ((q ^ (ra & 7)) << 4));
        const int rb = wc * 64 + m * 16 + la;
        b[m] = *(const bf16x8*)(Bs + rb * 128 + ((q ^ (rb & 7)) << 4));
      }
      #pragma unroll
      for (int m = 0; m < 4; ++m)
        #pragma unroll
        for (int n = 0; n < 4; ++n)
          acc[m][n] = __builtin_amdgcn_mfma_f32_16x16x32_bf16(a[m], b[n], acc[m][n], 0, 0, 0);
    }
  }

  // ---- epilogue: l2 -> e=exp2(l2*nc0s) -> e+e^2+e^4+e^8+e^16, signed sum ----
  f32x2 ks2 = {0.f, 0.f};
  #pragma unroll
  for (int m = 0; m < 4; ++m)
    #pragma unroll
    for (int n = 0; n < 4; ++n)
      #pragma unroll
      for (int h = 0; h < 2; ++h) {
        f32x2 g  = { acc[m][n][2 * h], acc[m][n][2 * h + 1] };
        f32x2 rc = { rsv[m * 4 + 2 * h] + cs[n], rsv[m * 4 + 2 * h + 1] + cs[n] };
        f32x2 l2 = __builtin_elementwise_max(rc - 2.f * g, (f32x2){0.f, 0.f});
        f32x2 tt = l2 * nc0s;
        f32x2 e;
        e[0] = __builtin_amdgcn_exp2f(tt[0]);
        e[1] = __builtin_amdgcn_exp2f(tt[1]);
        f32x2 s = e;
        f32x2 e2 = e * e;   s += e2;
        f32x2 e4 = e2 * e2; s += e4;
        f32x2 e8 = e4 * e4; s += e8;
        s += e8 * e8;
        ks2 += s;
      }
  float ksum = ks2[0] + ks2[1];
  #pragma unroll
  for (int m = 32; m >= 1; m >>= 1) ksum += __shfl_xor(ksum, m, 64);

  __syncthreads();                       // all waves done reading LDS tiles
  if (lane == 0) redf[w] = ksum;
  __syncthreads();
  if (t == 0) {
    const float sign = ((r < 32) == (c < 32)) ? 1.0f : -1.0f;
    const float mult = (r == c) ? 1.0f : 2.0f;
    block_out[bid] = (redf[0] + redf[1] + redf[2] + redf[3]) * sign * mult;
  }
}

// ---------------------------------------------------------------------------
// K3: reduce 2080 per-block partials (double) -> final scalar / 4096^2.
// ---------------------------------------------------------------------------
__global__ __launch_bounds__(256) void k_reduce(
    const float* __restrict__ block_out, float* __restrict__ out) {
  const int t = threadIdx.x, lane = t & 63, w = t >> 6;
  double s = 0.0;
  for (int i = t; i < 2080; i += 256) s += (double)block_out[i];
  #pragma unroll
  for (int m = 32; m >= 1; m >>= 1) s += __shfl_xor(s, m, 64);
  __shared__ double rd[4];
  if (lane == 0) rd[w] = s;
  __syncthreads();
  if (t == 0)
    out[0] = (float)((rd[0] + rd[1] + rd[2] + rd[3]) * (1.0 / 16777216.0));
}

// ---------------------------------------------------------------------------
extern "C" void kernel_launch(void* const* d_in, const int* in_sizes, int n_in,
                              void* d_out, int out_size, void* d_ws, size_t ws_size,
                              hipStream_t stream) {
  const float* src = (const float*)d_in[0];
  const float* tgt = (const float*)d_in[1];
  char* ws = (char*)d_ws;
  unsigned int*   done_prep = (unsigned int*)(ws + 24);
  float*          nc0s      = (float*)(ws + 32);
  float*          Spart     = (float*)(ws + 512);
  float*          partialT  = (float*)(ws + 1024);
  float*          sq        = (float*)(ws + 66560);
  float*          block_out = (float*)(ws + 99328);
  unsigned short* Vbf       = (unsigned short*)(ws + 131072);
  float* out = (float*)d_out;

  hipMemsetAsync(ws, 0, 64, stream);   // done_prep (+ legacy words)
  hipLaunchKernelGGL(k_prep,   dim3(64),   dim3(1024), 0, stream,
                     src, tgt, sq, Vbf, partialT, Spart, done_prep, nc0s);
  hipLaunchKernelGGL(k_main,   dim3(2080), dim3(256),  0, stream,
                     Vbf, sq, nc0s, block_out);
  hipLaunchKernelGGL(k_reduce, dim3(1),    dim3(256),  0, stream,
                     block_out, out);
}